// Round 2
// baseline (4971.879 us; speedup 1.0000x reference)
//
#include <hip/hip_runtime.h>
#include <hip/hip_bf16.h>

// BeamDecoder: greedy CVRP-style decode.
// Key identity: s_i(step) = c*( G[last,i] + (load/cap)*u_i + v_i )
//   G = (emb @ Wq[:, :H]^T) @ (emb @ Wk^T + bk)^T     [N,N]  (row = last)
//   u_i = K_i . Wq[:, H],  v_i = K_i . bq,  c = ALPHA/sqrt(H) = 0.015625
// Precompute G,u,v with fp32 GEMMs, then run the 2304-step sequential decode
// in ONE wave (64 lanes, no __syncthreads in the step loop).
// OUTPUT IS FLOAT32 (ref outputs int32 tour + fp32 scores -> promoted fp32).

#define NN 2048
#define HH 1024
#define TSTEPS (NN + NN / 8)   // 2304
#define TILE 64
#define KT 16

// ---------------- pack Wq[:, :H] into ld=1024 buffer ----------------
__global__ __launch_bounds__(256) void prep_wqh(const float* __restrict__ Wq,
                                                float* __restrict__ Wqh) {
  int id = blockIdx.x * 256 + threadIdx.x;     // 0 .. 1024*1024-1
  int r = id >> 10, c = id & 1023;
  Wqh[id] = Wq[r * (HH + 2) + c];
}

// ---------------- NT GEMM: C[M,N] = A[M,K] @ B[N,K]^T (+ bias[n]) ----------------
// grid.x = N/64, grid.y = M/64, 256 threads. All dims multiples of 64, K mult of 16.
__global__ __launch_bounds__(256) void gemm_nt(const float* __restrict__ A, int lda,
                                               const float* __restrict__ B, int ldb,
                                               float* __restrict__ C, int ldc,
                                               int K, const float* __restrict__ bias) {
  __shared__ float As[KT][TILE + 4];
  __shared__ float Bs[KT][TILE + 4];
  const int i0 = blockIdx.y * TILE;
  const int j0 = blockIdx.x * TILE;
  const int t = threadIdx.x;
  const int srow = t >> 2, sq = t & 3;   // staging: row 0..63, 4-float chunk 0..3
  const int tx = t & 15, ty = t >> 4;    // compute: 16x16 threads, 4x4 each
  float acc[4][4] = {};
  for (int k0 = 0; k0 < K; k0 += KT) {
    float4 av = *(const float4*)&A[(size_t)(i0 + srow) * lda + k0 + sq * 4];
    float4 bv = *(const float4*)&B[(size_t)(j0 + srow) * ldb + k0 + sq * 4];
    __syncthreads();
    As[sq * 4 + 0][srow] = av.x; As[sq * 4 + 1][srow] = av.y;
    As[sq * 4 + 2][srow] = av.z; As[sq * 4 + 3][srow] = av.w;
    Bs[sq * 4 + 0][srow] = bv.x; Bs[sq * 4 + 1][srow] = bv.y;
    Bs[sq * 4 + 2][srow] = bv.z; Bs[sq * 4 + 3][srow] = bv.w;
    __syncthreads();
#pragma unroll
    for (int k = 0; k < KT; ++k) {
      float4 a4 = *(const float4*)&As[k][ty * 4];
      float4 b4 = *(const float4*)&Bs[k][tx * 4];
      float a[4] = {a4.x, a4.y, a4.z, a4.w};
      float b[4] = {b4.x, b4.y, b4.z, b4.w};
#pragma unroll
      for (int m = 0; m < 4; ++m)
#pragma unroll
        for (int n = 0; n < 4; ++n) acc[m][n] = fmaf(a[m], b[n], acc[m][n]);
    }
  }
  float bb[4] = {0.f, 0.f, 0.f, 0.f};
  if (bias) {
#pragma unroll
    for (int n = 0; n < 4; ++n) bb[n] = bias[j0 + tx * 4 + n];
  }
#pragma unroll
  for (int m = 0; m < 4; ++m) {
    float4 st = {acc[m][0] + bb[0], acc[m][1] + bb[1], acc[m][2] + bb[2], acc[m][3] + bb[3]};
    *(float4*)&C[(size_t)(i0 + ty * 4 + m) * ldc + j0 + tx * 4] = st;
  }
}

// ---------------- u_i = K_i . Wq[:,H], v_i = K_i . bq  (one wave per row) ---------
__global__ __launch_bounds__(64) void uv_k(const float* __restrict__ Kmat,
                                           const float* __restrict__ Wq,
                                           const float* __restrict__ bq,
                                           float* __restrict__ u, float* __restrict__ v) {
  int i = blockIdx.x;
  int lane = threadIdx.x;
  float su = 0.f, sv = 0.f;
#pragma unroll
  for (int m = 0; m < HH / 64; ++m) {
    int j = lane + 64 * m;
    float kv = Kmat[(size_t)i * HH + j];
    su = fmaf(kv, Wq[(size_t)j * (HH + 2) + HH], su);
    sv = fmaf(kv, bq[j], sv);
  }
#pragma unroll
  for (int off = 32; off; off >>= 1) {
    su += __shfl_down(su, off, 64);
    sv += __shfl_down(sv, off, 64);
  }
  if (lane == 0) { u[i] = su; v[i] = sv; }
}

// ---------------- sequential decode: ONE wave, 64 lanes, 32 nodes/lane -----------
// Lane ownership: chunk c = r*64 + lane (r=0..7), nodes 4c .. 4c+3 (float4 loads,
// coalesced). Within a lane, (r,j) ascending == node index ascending, so strict >
// in the local scan gives first-max (jnp.argmax tie-break = smallest index).
__global__ __launch_bounds__(64) void decode(const float* __restrict__ GT,
                                             const float* __restrict__ u,
                                             const float* __restrict__ v,
                                             const float* __restrict__ demands,
                                             const int* __restrict__ capp,
                                             const int* __restrict__ depotp,
                                             float* __restrict__ out) {
  __shared__ float s_dem[NN];
  const int lane = threadIdx.x;
  for (int i = lane; i < NN; i += 64) s_dem[i] = demands[i];
  __syncthreads();

  const int depot = *depotp;
  const float capf = (float)(*capp);
  const float NEGINF = -__builtin_inff();
  const float C0 = 0.015625f;  // ALPHA / sqrt(HID), exact power of two

  float uu[32], vv[32], dd[32];
  unsigned vismask = 0;
#pragma unroll
  for (int r = 0; r < 8; ++r) {
    int c = r * 64 + lane;
    float4 u4 = ((const float4*)u)[c];
    float4 v4 = ((const float4*)v)[c];
    float4 d4 = ((const float4*)demands)[c];
    uu[r * 4 + 0] = u4.x; uu[r * 4 + 1] = u4.y; uu[r * 4 + 2] = u4.z; uu[r * 4 + 3] = u4.w;
    vv[r * 4 + 0] = v4.x; vv[r * 4 + 1] = v4.y; vv[r * 4 + 2] = v4.z; vv[r * 4 + 3] = v4.w;
    dd[r * 4 + 0] = d4.x; dd[r * 4 + 1] = d4.y; dd[r * 4 + 2] = d4.z; dd[r * 4 + 3] = d4.w;
#pragma unroll
    for (int j = 0; j < 4; ++j)
      if (4 * c + j == depot) vismask |= 1u << (r * 4 + j);
  }

  int last = depot, done = 0, ntaken = 0;
  float load = capf;
  if (lane == 0) out[0] = (float)depot;

  for (int step = 0; step < TSTEPS; ++step) {
    const float lr = load / capf;  // same fp32 division as reference
    const float4* rowp = (const float4*)(GT + (size_t)last * NN);
    float4 g[8];
#pragma unroll
    for (int r = 0; r < 8; ++r) g[r] = rowp[r * 64 + lane];

    float bv = NEGINF;
    int bi = NN;  // sentinel
#pragma unroll
    for (int r = 0; r < 8; ++r) {
      float gl[4] = {g[r].x, g[r].y, g[r].z, g[r].w};
#pragma unroll
      for (int j = 0; j < 4; ++j) {
        int k = r * 4 + j;
        float s = (gl[j] + uu[k] * lr + vv[k]) * C0;
        bool feas = !((vismask >> k) & 1u) && (dd[k] <= load);
        if (feas && s > bv) { bv = s; bi = 4 * (r * 64 + lane) + j; }
      }
    }
    // butterfly: every lane ends with the global (max, smallest-index) pair
#pragma unroll
    for (int off = 1; off < 64; off <<= 1) {
      float ov = __shfl_xor(bv, off, 64);
      int oi = __shfl_xor(bi, off, 64);
      if (ov > bv || (ov == bv && oi < bi)) { bv = ov; bi = oi; }
    }

    const int take = (bv > NEGINF) && !done;
    const int nxt = take ? bi : depot;
    if (lane == 0) {
      out[1 + step] = (float)nxt;
      out[1 + TSTEPS + step] = take ? bv : 0.0f;
    }
    if (take) {
      load = load - s_dem[bi];  // LDS broadcast read; same fp32 op as reference
      ntaken++;
      int c = bi >> 2;
      if ((c & 63) == lane) vismask |= 1u << ((c >> 6) * 4 + (bi & 3));
    } else {
      load = capf;
      if (ntaken == NN - 1) done = 1;  // all customers served
    }
    last = nxt;
  }
}

extern "C" void kernel_launch(void* const* d_in, const int* in_sizes, int n_in,
                              void* d_out, int out_size, void* d_ws, size_t ws_size,
                              hipStream_t stream) {
  const float* emb     = (const float*)d_in[0];  // [N, H]
  const float* demands = (const float*)d_in[1];  // [N]
  const float* Wq      = (const float*)d_in[2];  // [H, H+2]
  const float* bq      = (const float*)d_in[3];  // [H]
  const float* Wk      = (const float*)d_in[4];  // [H, H]
  const float* bk      = (const float*)d_in[5];  // [H]
  const int* cap       = (const int*)d_in[6];
  const int* depot     = (const int*)d_in[7];
  float* out           = (float*)d_out;          // 2305 tour + 2304 scores, fp32

  char* ws = (char*)d_ws;
  float* Kmat = (float*)(ws);                         // 8 MB  [N,H]
  float* Z    = (float*)(ws + ((size_t)8 << 20));     // 8 MB  [N,H]
  float* GT   = (float*)(ws + ((size_t)16 << 20));    // 16 MB [N,N] row=last
  float* Wqh  = (float*)(ws + ((size_t)32 << 20));    // 4 MB  [H,H]
  float* u    = (float*)(ws + ((size_t)36 << 20));    // 8 KB
  float* v    = (float*)(ws + ((size_t)36 << 20) + 8192);

  hipLaunchKernelGGL(prep_wqh, dim3(4096), dim3(256), 0, stream, Wq, Wqh);
  // K = emb @ Wk^T + bk
  hipLaunchKernelGGL(gemm_nt, dim3(HH / TILE, NN / TILE), dim3(256), 0, stream,
                     emb, HH, Wk, HH, Kmat, HH, HH, bk);
  // Z = emb @ Wqh^T
  hipLaunchKernelGGL(gemm_nt, dim3(HH / TILE, NN / TILE), dim3(256), 0, stream,
                     emb, HH, Wqh, HH, Z, HH, HH, (const float*)nullptr);
  // GT = Z @ K^T   (GT[last, i])
  hipLaunchKernelGGL(gemm_nt, dim3(NN / TILE, NN / TILE), dim3(256), 0, stream,
                     Z, HH, Kmat, HH, GT, NN, HH, (const float*)nullptr);
  hipLaunchKernelGGL(uv_k, dim3(NN), dim3(64), 0, stream, Kmat, Wq, bq, u, v);
  hipLaunchKernelGGL(decode, dim3(1), dim3(64), 0, stream, GT, u, v, demands,
                     cap, depot, out);
}

// Round 3
// 3708.799 us; speedup vs baseline: 1.3406x; 1.3406x over previous
//
#include <hip/hip_runtime.h>
#include <hip/hip_bf16.h>

// BeamDecoder: greedy CVRP-style decode.
// Key identity: s_i(step) = c*( G[last,i] + (load/cap)*u_i + v_i )
//   G = (emb @ Wq[:, :H]^T) @ (emb @ Wk^T + bk)^T     [N,N]  (row = last)
//   u_i = K_i . Wq[:, H],  v_i = K_i . bq,  c = ALPHA/sqrt(H) = 0.015625
// Precompute G,u,v with fp32 GEMMs, then run the 2304-step sequential decode
// in ONE wave (64 lanes, no __syncthreads in the step loop).
// R3 fix: round 2 spilled (VGPR=84 vs ~130 live floats) -> 8 KB/step scratch
// round-trip (WRITE_SIZE 18 MB). Now only uu[32] lives in VGPRs; vv/dd/dem
// live in LDS (ds_read addresses independent of `last` -> overlap global
// latency); visited folded into dd via dd[node]=+inf. __launch_bounds__(64,1).

#define NN 2048
#define HH 1024
#define TSTEPS (NN + NN / 8)   // 2304
#define TILE 64
#define KT 16

// ---------------- pack Wq[:, :H] into ld=1024 buffer ----------------
__global__ __launch_bounds__(256) void prep_wqh(const float* __restrict__ Wq,
                                                float* __restrict__ Wqh) {
  int id = blockIdx.x * 256 + threadIdx.x;     // 0 .. 1024*1024-1
  int r = id >> 10, c = id & 1023;
  Wqh[id] = Wq[r * (HH + 2) + c];
}

// ---------------- NT GEMM: C[M,N] = A[M,K] @ B[N,K]^T (+ bias[n]) ----------------
__global__ __launch_bounds__(256) void gemm_nt(const float* __restrict__ A, int lda,
                                               const float* __restrict__ B, int ldb,
                                               float* __restrict__ C, int ldc,
                                               int K, const float* __restrict__ bias) {
  __shared__ float As[KT][TILE + 4];
  __shared__ float Bs[KT][TILE + 4];
  const int i0 = blockIdx.y * TILE;
  const int j0 = blockIdx.x * TILE;
  const int t = threadIdx.x;
  const int srow = t >> 2, sq = t & 3;
  const int tx = t & 15, ty = t >> 4;
  float acc[4][4] = {};
  for (int k0 = 0; k0 < K; k0 += KT) {
    float4 av = *(const float4*)&A[(size_t)(i0 + srow) * lda + k0 + sq * 4];
    float4 bv = *(const float4*)&B[(size_t)(j0 + srow) * ldb + k0 + sq * 4];
    __syncthreads();
    As[sq * 4 + 0][srow] = av.x; As[sq * 4 + 1][srow] = av.y;
    As[sq * 4 + 2][srow] = av.z; As[sq * 4 + 3][srow] = av.w;
    Bs[sq * 4 + 0][srow] = bv.x; Bs[sq * 4 + 1][srow] = bv.y;
    Bs[sq * 4 + 2][srow] = bv.z; Bs[sq * 4 + 3][srow] = bv.w;
    __syncthreads();
#pragma unroll
    for (int k = 0; k < KT; ++k) {
      float4 a4 = *(const float4*)&As[k][ty * 4];
      float4 b4 = *(const float4*)&Bs[k][tx * 4];
      float a[4] = {a4.x, a4.y, a4.z, a4.w};
      float b[4] = {b4.x, b4.y, b4.z, b4.w};
#pragma unroll
      for (int m = 0; m < 4; ++m)
#pragma unroll
        for (int n = 0; n < 4; ++n) acc[m][n] = fmaf(a[m], b[n], acc[m][n]);
    }
  }
  float bb[4] = {0.f, 0.f, 0.f, 0.f};
  if (bias) {
#pragma unroll
    for (int n = 0; n < 4; ++n) bb[n] = bias[j0 + tx * 4 + n];
  }
#pragma unroll
  for (int m = 0; m < 4; ++m) {
    float4 st = {acc[m][0] + bb[0], acc[m][1] + bb[1], acc[m][2] + bb[2], acc[m][3] + bb[3]};
    *(float4*)&C[(size_t)(i0 + ty * 4 + m) * ldc + j0 + tx * 4] = st;
  }
}

// ---------------- u_i = K_i . Wq[:,H], v_i = K_i . bq  (one wave per row) ---------
__global__ __launch_bounds__(64) void uv_k(const float* __restrict__ Kmat,
                                           const float* __restrict__ Wq,
                                           const float* __restrict__ bq,
                                           float* __restrict__ u, float* __restrict__ v) {
  int i = blockIdx.x;
  int lane = threadIdx.x;
  float su = 0.f, sv = 0.f;
#pragma unroll
  for (int m = 0; m < HH / 64; ++m) {
    int j = lane + 64 * m;
    float kv = Kmat[(size_t)i * HH + j];
    su = fmaf(kv, Wq[(size_t)j * (HH + 2) + HH], su);
    sv = fmaf(kv, bq[j], sv);
  }
#pragma unroll
  for (int off = 32; off; off >>= 1) {
    su += __shfl_down(su, off, 64);
    sv += __shfl_down(sv, off, 64);
  }
  if (lane == 0) { u[i] = su; v[i] = sv; }
}

// ---------------- sequential decode: ONE wave, 64 lanes, 32 nodes/lane -----------
// Lane owns chunks c = r*64+lane (r=0..7), nodes 4c..4c+3 (coalesced float4).
// Only uu[32] in VGPRs; vv/dd/dem in LDS. dd[node]=+inf encodes visited.
__global__ __launch_bounds__(64, 1) void decode(const float* __restrict__ GT,
                                                const float* __restrict__ u,
                                                const float* __restrict__ v,
                                                const float* __restrict__ demands,
                                                const int* __restrict__ capp,
                                                const int* __restrict__ depotp,
                                                float* __restrict__ out) {
  __shared__ __align__(16) float s_dem[NN];  // raw demands (for load update)
  __shared__ __align__(16) float s_dd[NN];   // demands, +inf when visited
  __shared__ __align__(16) float s_vv[NN];   // v_i
  const int lane = threadIdx.x;
  const int depot = *depotp;
  const float capf = (float)(*capp);
  const float INF = __builtin_inff();
  const float NEGINF = -INF;
  const float C0 = 0.015625f;  // ALPHA / sqrt(HID), exact power of two

  for (int i = lane; i < NN; i += 64) {
    float d = demands[i];
    s_dem[i] = d;
    s_dd[i] = d;
    s_vv[i] = v[i];
  }
  __syncthreads();
  if (lane == 0) s_dd[depot] = INF;  // depot starts visited

  float uu[32];
#pragma unroll
  for (int r = 0; r < 8; ++r) {
    float4 u4 = ((const float4*)u)[r * 64 + lane];
    uu[r * 4 + 0] = u4.x; uu[r * 4 + 1] = u4.y;
    uu[r * 4 + 2] = u4.z; uu[r * 4 + 3] = u4.w;
  }

  int last = depot, done = 0, ntaken = 0;
  float load = capf;
  if (lane == 0) out[0] = (float)depot;

  const float4* dd4 = (const float4*)s_dd;
  const float4* vv4 = (const float4*)s_vv;

  for (int step = 0; step < TSTEPS; ++step) {
    const float lr = load / capf;  // same fp32 division as reference
    const float4* rowp = (const float4*)(GT + (size_t)last * NN);
    float4 g[8];
#pragma unroll
    for (int r = 0; r < 8; ++r) g[r] = rowp[r * 64 + lane];

    float bv = NEGINF;
    int bi = NN;  // sentinel
#pragma unroll
    for (int r = 0; r < 8; ++r) {
      float4 d4 = dd4[r * 64 + lane];
      float4 v4 = vv4[r * 64 + lane];
      float gl[4] = {g[r].x, g[r].y, g[r].z, g[r].w};
      float dl[4] = {d4.x, d4.y, d4.z, d4.w};
      float vl[4] = {v4.x, v4.y, v4.z, v4.w};
#pragma unroll
      for (int j = 0; j < 4; ++j) {
        int k = r * 4 + j;
        float s = (gl[j] + uu[k] * lr + vl[j]) * C0;  // verbatim round-2 expr
        bool feas = (dl[j] <= load);                  // +inf == visited
        if (feas && s > bv) { bv = s; bi = 4 * (r * 64 + lane) + j; }
      }
    }
    // butterfly: every lane ends with the global (max, smallest-index) pair
#pragma unroll
    for (int off = 1; off < 64; off <<= 1) {
      float ov = __shfl_xor(bv, off, 64);
      int oi = __shfl_xor(bi, off, 64);
      if (ov > bv || (ov == bv && oi < bi)) { bv = ov; bi = oi; }
    }

    const int take = (bv > NEGINF) && !done;
    const int nxt = take ? bi : depot;
    if (lane == 0) {
      out[1 + step] = (float)nxt;
      out[1 + TSTEPS + step] = take ? bv : 0.0f;
    }
    if (take) {
      load = load - s_dem[bi];  // broadcast LDS read; same fp32 op as reference
      ntaken++;
      if (lane == 0) s_dd[bi] = INF;  // mark visited (in-wave ds ordering)
    } else {
      load = capf;
      if (ntaken == NN - 1) done = 1;  // all customers served
    }
    last = nxt;
  }
}

extern "C" void kernel_launch(void* const* d_in, const int* in_sizes, int n_in,
                              void* d_out, int out_size, void* d_ws, size_t ws_size,
                              hipStream_t stream) {
  const float* emb     = (const float*)d_in[0];  // [N, H]
  const float* demands = (const float*)d_in[1];  // [N]
  const float* Wq      = (const float*)d_in[2];  // [H, H+2]
  const float* bq      = (const float*)d_in[3];  // [H]
  const float* Wk      = (const float*)d_in[4];  // [H, H]
  const float* bk      = (const float*)d_in[5];  // [H]
  const int* cap       = (const int*)d_in[6];
  const int* depot     = (const int*)d_in[7];
  float* out           = (float*)d_out;          // 2305 tour + 2304 scores, fp32

  char* ws = (char*)d_ws;
  float* Kmat = (float*)(ws);                         // 8 MB  [N,H]
  float* Z    = (float*)(ws + ((size_t)8 << 20));     // 8 MB  [N,H]
  float* GT   = (float*)(ws + ((size_t)16 << 20));    // 16 MB [N,N] row=last
  float* Wqh  = (float*)(ws + ((size_t)32 << 20));    // 4 MB  [H,H]
  float* u    = (float*)(ws + ((size_t)36 << 20));    // 8 KB
  float* v    = (float*)(ws + ((size_t)36 << 20) + 8192);

  hipLaunchKernelGGL(prep_wqh, dim3(4096), dim3(256), 0, stream, Wq, Wqh);
  // K = emb @ Wk^T + bk
  hipLaunchKernelGGL(gemm_nt, dim3(HH / TILE, NN / TILE), dim3(256), 0, stream,
                     emb, HH, Wk, HH, Kmat, HH, HH, bk);
  // Z = emb @ Wqh^T
  hipLaunchKernelGGL(gemm_nt, dim3(HH / TILE, NN / TILE), dim3(256), 0, stream,
                     emb, HH, Wqh, HH, Z, HH, HH, (const float*)nullptr);
  // GT = Z @ K^T   (GT[last, i])
  hipLaunchKernelGGL(gemm_nt, dim3(NN / TILE, NN / TILE), dim3(256), 0, stream,
                     Z, HH, Kmat, HH, GT, NN, HH, (const float*)nullptr);
  hipLaunchKernelGGL(uv_k, dim3(NN), dim3(64), 0, stream, Kmat, Wq, bq, u, v);
  hipLaunchKernelGGL(decode, dim3(1), dim3(64), 0, stream, GT, u, v, demands,
                     cap, depot, out);
}

// Round 4
// 3552.718 us; speedup vs baseline: 1.3995x; 1.0439x over previous
//
#include <hip/hip_runtime.h>
#include <hip/hip_bf16.h>

// BeamDecoder: greedy CVRP-style decode.
// Key identity: s_i(step) = c*( G[last,i] + (load/cap)*u_i + v_i )
//   G = (emb @ Wq[:, :H]^T) @ (emb @ Wk^T + bk)^T     [N,N]  (row = last)
//   u_i = K_i . Wq[:, H],  v_i = K_i . bq,  c = ALPHA/sqrt(H) = 0.015625
// R4: (a) v folded into GT via GEMM bias (v==0 since bq==0 -> bit-identical),
//     (b) compare unscaled t = g + u*lr (C0 is exact 2^-6, order-preserving;
//         applied once to the winner -> identical emitted bits),
//     (c) done-tail fast path (ref emits (depot,0) forever once done),
//     (d) depot GT row cached in LDS (route closings + step 0),
//     (e) per-quad max chains + ordered merge (shorter dep chain).
// Decode runs in ONE wave; no __syncthreads in the step loop.

#define NN 2048
#define HH 1024
#define TSTEPS (NN + NN / 8)   // 2304
#define TILE 64
#define KT 16

// ---------------- pack Wq[:, :H] into ld=1024 buffer ----------------
__global__ __launch_bounds__(256) void prep_wqh(const float* __restrict__ Wq,
                                                float* __restrict__ Wqh) {
  int id = blockIdx.x * 256 + threadIdx.x;     // 0 .. 1024*1024-1
  int r = id >> 10, c = id & 1023;
  Wqh[id] = Wq[r * (HH + 2) + c];
}

// ---------------- NT GEMM: C[M,N] = A[M,K] @ B[N,K]^T (+ bias[n]) ----------------
__global__ __launch_bounds__(256) void gemm_nt(const float* __restrict__ A, int lda,
                                               const float* __restrict__ B, int ldb,
                                               float* __restrict__ C, int ldc,
                                               int K, const float* __restrict__ bias) {
  __shared__ float As[KT][TILE + 4];
  __shared__ float Bs[KT][TILE + 4];
  const int i0 = blockIdx.y * TILE;
  const int j0 = blockIdx.x * TILE;
  const int t = threadIdx.x;
  const int srow = t >> 2, sq = t & 3;
  const int tx = t & 15, ty = t >> 4;
  float acc[4][4] = {};
  for (int k0 = 0; k0 < K; k0 += KT) {
    float4 av = *(const float4*)&A[(size_t)(i0 + srow) * lda + k0 + sq * 4];
    float4 bv = *(const float4*)&B[(size_t)(j0 + srow) * ldb + k0 + sq * 4];
    __syncthreads();
    As[sq * 4 + 0][srow] = av.x; As[sq * 4 + 1][srow] = av.y;
    As[sq * 4 + 2][srow] = av.z; As[sq * 4 + 3][srow] = av.w;
    Bs[sq * 4 + 0][srow] = bv.x; Bs[sq * 4 + 1][srow] = bv.y;
    Bs[sq * 4 + 2][srow] = bv.z; Bs[sq * 4 + 3][srow] = bv.w;
    __syncthreads();
#pragma unroll
    for (int k = 0; k < KT; ++k) {
      float4 a4 = *(const float4*)&As[k][ty * 4];
      float4 b4 = *(const float4*)&Bs[k][tx * 4];
      float a[4] = {a4.x, a4.y, a4.z, a4.w};
      float b[4] = {b4.x, b4.y, b4.z, b4.w};
#pragma unroll
      for (int m = 0; m < 4; ++m)
#pragma unroll
        for (int n = 0; n < 4; ++n) acc[m][n] = fmaf(a[m], b[n], acc[m][n]);
    }
  }
  float bb[4] = {0.f, 0.f, 0.f, 0.f};
  if (bias) {
#pragma unroll
    for (int n = 0; n < 4; ++n) bb[n] = bias[j0 + tx * 4 + n];
  }
#pragma unroll
  for (int m = 0; m < 4; ++m) {
    float4 st = {acc[m][0] + bb[0], acc[m][1] + bb[1], acc[m][2] + bb[2], acc[m][3] + bb[3]};
    *(float4*)&C[(size_t)(i0 + ty * 4 + m) * ldc + j0 + tx * 4] = st;
  }
}

// ---------------- u_i = K_i . Wq[:,H], v_i = K_i . bq  (one wave per row) ---------
__global__ __launch_bounds__(64) void uv_k(const float* __restrict__ Kmat,
                                           const float* __restrict__ Wq,
                                           const float* __restrict__ bq,
                                           float* __restrict__ u, float* __restrict__ v) {
  int i = blockIdx.x;
  int lane = threadIdx.x;
  float su = 0.f, sv = 0.f;
#pragma unroll
  for (int m = 0; m < HH / 64; ++m) {
    int j = lane + 64 * m;
    float kv = Kmat[(size_t)i * HH + j];
    su = fmaf(kv, Wq[(size_t)j * (HH + 2) + HH], su);
    sv = fmaf(kv, bq[j], sv);
  }
#pragma unroll
  for (int off = 32; off; off >>= 1) {
    su += __shfl_down(su, off, 64);
    sv += __shfl_down(sv, off, 64);
  }
  if (lane == 0) { u[i] = su; v[i] = sv; }
}

// ---------------- sequential decode: ONE wave, 64 lanes, 32 nodes/lane -----------
// Lane owns chunks c = r*64+lane (r=0..7), nodes 4c..4c+3 (coalesced float4).
// uu[32] in VGPRs; dd (demands, +inf=visited) in LDS; GT row has v pre-added.
__global__ __launch_bounds__(64, 1) void decode(const float* __restrict__ GT,
                                                const float* __restrict__ u,
                                                const float* __restrict__ demands,
                                                const int* __restrict__ capp,
                                                const int* __restrict__ depotp,
                                                float* __restrict__ out) {
  __shared__ __align__(16) float s_dem[NN];   // raw demands (for load update)
  __shared__ __align__(16) float s_dd[NN];    // demands, +inf when visited
  __shared__ __align__(16) float s_drow[NN];  // GT[depot,:] cached
  const int lane = threadIdx.x;
  const int depot = *depotp;
  const float capf = (float)(*capp);
  const float INF = __builtin_inff();
  const float NEGINF = -INF;
  const float C0 = 0.015625f;  // ALPHA / sqrt(HID), exact power of two

  for (int i = lane; i < NN; i += 64) {
    float d = demands[i];
    s_dem[i] = d;
    s_dd[i] = d;
    s_drow[i] = GT[(size_t)depot * NN + i];
  }
  __syncthreads();
  if (lane == 0) s_dd[depot] = INF;  // depot starts visited

  float uu[32];
#pragma unroll
  for (int r = 0; r < 8; ++r) {
    float4 u4 = ((const float4*)u)[r * 64 + lane];
    uu[r * 4 + 0] = u4.x; uu[r * 4 + 1] = u4.y;
    uu[r * 4 + 2] = u4.z; uu[r * 4 + 3] = u4.w;
  }

  int last = depot, done = 0, ntaken = 0;
  float load = capf;
  if (lane == 0) out[0] = (float)depot;

  const float4* dd4 = (const float4*)s_dd;
  const float4* dr4 = (const float4*)s_drow;

  for (int step = 0; step < TSTEPS; ++step) {
    if (done) {  // ref emits (depot, 0) forever once done — bulk-fill and exit
      const float df = (float)depot;
      for (int q = step + lane; q < TSTEPS; q += 64) {
        out[1 + q] = df;
        out[1 + TSTEPS + q] = 0.0f;
      }
      break;
    }
    const float lr = load / capf;  // same fp32 division as reference
    const int lasts = __builtin_amdgcn_readfirstlane(last);  // wave-uniform
    float4 g[8];
    if (lasts == depot) {
#pragma unroll
      for (int r = 0; r < 8; ++r) g[r] = dr4[r * 64 + lane];
    } else {
      const float4* rowp = (const float4*)(GT + (size_t)lasts * NN);
#pragma unroll
      for (int r = 0; r < 8; ++r) g[r] = rowp[r * 64 + lane];
    }

    float bv = NEGINF;
    int bi = NN;  // sentinel
#pragma unroll
    for (int r = 0; r < 8; ++r) {
      float4 d4 = dd4[r * 64 + lane];
      float gl[4] = {g[r].x, g[r].y, g[r].z, g[r].w};
      float dl[4] = {d4.x, d4.y, d4.z, d4.w};
      float cv = NEGINF;
      int cj = 0;
#pragma unroll
      for (int j = 0; j < 4; ++j) {
        // unscaled score: *C0 (exact 2^-6) deferred to the winner — same order
        float tt = fmaf(uu[r * 4 + j], lr, gl[j]);
        bool feas = (dl[j] <= load);  // +inf == visited
        if (feas && tt > cv) { cv = tt; cj = j; }
      }
      // merge in ascending r: strict > keeps the smallest index on ties
      if (cv > bv) { bv = cv; bi = 4 * (r * 64 + lane) + cj; }
    }
    // butterfly: every lane ends with the global (max, smallest-index) pair
#pragma unroll
    for (int off = 1; off < 64; off <<= 1) {
      float ov = __shfl_xor(bv, off, 64);
      int oi = __shfl_xor(bi, off, 64);
      if (ov > bv || (ov == bv && oi < bi)) { bv = ov; bi = oi; }
    }

    const int take = (bv > NEGINF);
    const int nxt = take ? bi : depot;
    if (lane == 0) {
      out[1 + step] = (float)nxt;
      out[1 + TSTEPS + step] = take ? bv * C0 : 0.0f;  // exact pow2 scale
    }
    if (take) {
      load = load - s_dem[bi];  // broadcast LDS read; same fp32 op as reference
      ntaken++;
      if (lane == 0) s_dd[bi] = INF;  // mark visited
    } else {
      load = capf;
      if (ntaken == NN - 1) done = 1;  // all customers served
    }
    last = nxt;
  }
}

extern "C" void kernel_launch(void* const* d_in, const int* in_sizes, int n_in,
                              void* d_out, int out_size, void* d_ws, size_t ws_size,
                              hipStream_t stream) {
  const float* emb     = (const float*)d_in[0];  // [N, H]
  const float* demands = (const float*)d_in[1];  // [N]
  const float* Wq      = (const float*)d_in[2];  // [H, H+2]
  const float* bq      = (const float*)d_in[3];  // [H]
  const float* Wk      = (const float*)d_in[4];  // [H, H]
  const float* bk      = (const float*)d_in[5];  // [H]
  const int* cap       = (const int*)d_in[6];
  const int* depot     = (const int*)d_in[7];
  float* out           = (float*)d_out;          // 2305 tour + 2304 scores, fp32

  char* ws = (char*)d_ws;
  float* Kmat = (float*)(ws);                         // 8 MB  [N,H]
  float* Z    = (float*)(ws + ((size_t)8 << 20));     // 8 MB  [N,H]
  float* GT   = (float*)(ws + ((size_t)16 << 20));    // 16 MB [N,N] row=last, +v
  float* Wqh  = (float*)(ws + ((size_t)32 << 20));    // 4 MB  [H,H]
  float* u    = (float*)(ws + ((size_t)36 << 20));    // 8 KB
  float* v    = (float*)(ws + ((size_t)36 << 20) + 8192);

  hipLaunchKernelGGL(prep_wqh, dim3(4096), dim3(256), 0, stream, Wq, Wqh);
  // K = emb @ Wk^T + bk
  hipLaunchKernelGGL(gemm_nt, dim3(HH / TILE, NN / TILE), dim3(256), 0, stream,
                     emb, HH, Wk, HH, Kmat, HH, HH, bk);
  // Z = emb @ Wqh^T
  hipLaunchKernelGGL(gemm_nt, dim3(HH / TILE, NN / TILE), dim3(256), 0, stream,
                     emb, HH, Wqh, HH, Z, HH, HH, (const float*)nullptr);
  // u_i = K_i . Wq[:,H], v_i = K_i . bq   (before GT GEMM: v is its bias)
  hipLaunchKernelGGL(uv_k, dim3(NN), dim3(64), 0, stream, Kmat, Wq, bq, u, v);
  // GT = Z @ K^T + v   (GT[last, i]; v==0 here since bq==0 -> bit-identical)
  hipLaunchKernelGGL(gemm_nt, dim3(NN / TILE, NN / TILE), dim3(256), 0, stream,
                     Z, HH, Kmat, HH, GT, NN, HH, v);
  hipLaunchKernelGGL(decode, dim3(1), dim3(64), 0, stream, GT, u, demands,
                     cap, depot, out);
}

// Round 5
// 2943.925 us; speedup vs baseline: 1.6889x; 1.2068x over previous
//
#include <hip/hip_runtime.h>
#include <hip/hip_bf16.h>

// BeamDecoder: greedy CVRP-style decode.
// Key identity: s_i(step) = c*( G[last,i] + (load/cap)*u_i + v_i )
//   G = (emb @ Wq[:, :H]^T) @ (emb @ Wk^T + bk)^T     [N,N]  (row = last)
//   u_i = K_i . Wq[:, H],  v_i = K_i . bq,  c = ALPHA/sqrt(H) = 0.015625
// R5: decode is a serial latency chain (per-step VALU cuts in R4 changed
// nothing). Changes: (1) DPP argmax (row_shr 1/2/4/8 + bcast15/31, ~100 cyc)
// replaces the 6-level ds_bpermute butterfly (~700 cyc); (2) outputs buffered
// in LDS, flushed once (no per-step global stores on the vmcnt chain);
// (3) next-row prefetch issued right after readlane so bookkeeping hides
// under the load shadow. Selection math bit-identical to R3/R4.

#define NN 2048
#define HH 1024
#define TSTEPS (NN + NN / 8)   // 2304
#define TILE 64
#define KT 16

// ---------------- pack Wq[:, :H] into ld=1024 buffer ----------------
__global__ __launch_bounds__(256) void prep_wqh(const float* __restrict__ Wq,
                                                float* __restrict__ Wqh) {
  int id = blockIdx.x * 256 + threadIdx.x;     // 0 .. 1024*1024-1
  int r = id >> 10, c = id & 1023;
  Wqh[id] = Wq[r * (HH + 2) + c];
}

// ---------------- NT GEMM: C[M,N] = A[M,K] @ B[N,K]^T (+ bias[n]) ----------------
__global__ __launch_bounds__(256) void gemm_nt(const float* __restrict__ A, int lda,
                                               const float* __restrict__ B, int ldb,
                                               float* __restrict__ C, int ldc,
                                               int K, const float* __restrict__ bias) {
  __shared__ float As[KT][TILE + 4];
  __shared__ float Bs[KT][TILE + 4];
  const int i0 = blockIdx.y * TILE;
  const int j0 = blockIdx.x * TILE;
  const int t = threadIdx.x;
  const int srow = t >> 2, sq = t & 3;
  const int tx = t & 15, ty = t >> 4;
  float acc[4][4] = {};
  for (int k0 = 0; k0 < K; k0 += KT) {
    float4 av = *(const float4*)&A[(size_t)(i0 + srow) * lda + k0 + sq * 4];
    float4 bv = *(const float4*)&B[(size_t)(j0 + srow) * ldb + k0 + sq * 4];
    __syncthreads();
    As[sq * 4 + 0][srow] = av.x; As[sq * 4 + 1][srow] = av.y;
    As[sq * 4 + 2][srow] = av.z; As[sq * 4 + 3][srow] = av.w;
    Bs[sq * 4 + 0][srow] = bv.x; Bs[sq * 4 + 1][srow] = bv.y;
    Bs[sq * 4 + 2][srow] = bv.z; Bs[sq * 4 + 3][srow] = bv.w;
    __syncthreads();
#pragma unroll
    for (int k = 0; k < KT; ++k) {
      float4 a4 = *(const float4*)&As[k][ty * 4];
      float4 b4 = *(const float4*)&Bs[k][tx * 4];
      float a[4] = {a4.x, a4.y, a4.z, a4.w};
      float b[4] = {b4.x, b4.y, b4.z, b4.w};
#pragma unroll
      for (int m = 0; m < 4; ++m)
#pragma unroll
        for (int n = 0; n < 4; ++n) acc[m][n] = fmaf(a[m], b[n], acc[m][n]);
    }
  }
  float bb[4] = {0.f, 0.f, 0.f, 0.f};
  if (bias) {
#pragma unroll
    for (int n = 0; n < 4; ++n) bb[n] = bias[j0 + tx * 4 + n];
  }
#pragma unroll
  for (int m = 0; m < 4; ++m) {
    float4 st = {acc[m][0] + bb[0], acc[m][1] + bb[1], acc[m][2] + bb[2], acc[m][3] + bb[3]};
    *(float4*)&C[(size_t)(i0 + ty * 4 + m) * ldc + j0 + tx * 4] = st;
  }
}

// ---------------- u_i = K_i . Wq[:,H], v_i = K_i . bq  (one wave per row) ---------
__global__ __launch_bounds__(64) void uv_k(const float* __restrict__ Kmat,
                                           const float* __restrict__ Wq,
                                           const float* __restrict__ bq,
                                           float* __restrict__ u, float* __restrict__ v) {
  int i = blockIdx.x;
  int lane = threadIdx.x;
  float su = 0.f, sv = 0.f;
#pragma unroll
  for (int m = 0; m < HH / 64; ++m) {
    int j = lane + 64 * m;
    float kv = Kmat[(size_t)i * HH + j];
    su = fmaf(kv, Wq[(size_t)j * (HH + 2) + HH], su);
    sv = fmaf(kv, bq[j], sv);
  }
#pragma unroll
  for (int off = 32; off; off >>= 1) {
    su += __shfl_down(su, off, 64);
    sv += __shfl_down(sv, off, 64);
  }
  if (lane == 0) { u[i] = su; v[i] = sv; }
}

// DPP-combine: merge (bv,bi) with the pair pulled through DPP ctrl CTRL.
// Invalid-source lanes get (-inf, INT_MAX) so they can never win.
#define DPP_MERGE(CTRL)                                                       \
  {                                                                           \
    int ovb = __builtin_amdgcn_update_dpp(                                    \
        (int)0xFF800000, __float_as_int(bv), (CTRL), 0xf, 0xf, false);        \
    int oib = __builtin_amdgcn_update_dpp(                                    \
        0x7fffffff, bi, (CTRL), 0xf, 0xf, false);                             \
    float ov = __int_as_float(ovb);                                           \
    if (ov > bv || (ov == bv && oib < bi)) { bv = ov; bi = oib; }             \
  }

// ---------------- sequential decode: ONE wave, 64 lanes, 32 nodes/lane -----------
// Lane owns chunks c = r*64+lane (r=0..7), nodes 4c..4c+3 (coalesced float4).
// uu[32] in VGPRs; dd (demands, +inf=visited) in LDS; GT row has v pre-added.
__global__ __launch_bounds__(64, 1) void decode(const float* __restrict__ GT,
                                                const float* __restrict__ u,
                                                const float* __restrict__ demands,
                                                const int* __restrict__ capp,
                                                const int* __restrict__ depotp,
                                                float* __restrict__ out) {
  __shared__ __align__(16) float s_dem[NN];    // raw demands (for load update)
  __shared__ __align__(16) float s_dd[NN];     // demands, +inf when visited
  __shared__ __align__(16) float s_drow[NN];   // GT[depot,:] cached
  __shared__ __align__(16) float s_tour[TSTEPS + 1];
  __shared__ __align__(16) float s_scr[TSTEPS];
  const int lane = threadIdx.x;
  const int depot = *depotp;
  const float capf = (float)(*capp);
  const float INF = __builtin_inff();
  const float NEGINF = -INF;
  const float C0 = 0.015625f;  // ALPHA / sqrt(HID), exact power of two

  for (int i = lane; i < NN; i += 64) {
    float d = demands[i];
    s_dem[i] = d;
    s_dd[i] = d;
    s_drow[i] = GT[(size_t)depot * NN + i];
  }
  __syncthreads();
  if (lane == 0) {
    s_dd[depot] = INF;  // depot starts visited
    s_tour[0] = (float)depot;
  }

  float uu[32];
#pragma unroll
  for (int r = 0; r < 8; ++r) {
    float4 u4 = ((const float4*)u)[r * 64 + lane];
    uu[r * 4 + 0] = u4.x; uu[r * 4 + 1] = u4.y;
    uu[r * 4 + 2] = u4.z; uu[r * 4 + 3] = u4.w;
  }

  const float4* dd4 = (const float4*)s_dd;
  const float4* dr4 = (const float4*)s_drow;

  int done = 0, ntaken = 0;
  float load = capf;
  float lr = load / capf;  // same fp32 division as reference
  float4 g[8];
#pragma unroll
  for (int r = 0; r < 8; ++r) g[r] = dr4[r * 64 + lane];  // row[depot] for step 0

  for (int step = 0; step < TSTEPS; ++step) {
    if (done) {  // ref emits (depot, 0) forever once done — bulk-fill and exit
      const float df = (float)depot;
      for (int q = step + lane; q < TSTEPS; q += 64) {
        s_tour[1 + q] = df;
        s_scr[q] = 0.0f;
      }
      break;
    }
    // ---- score scan over this lane's 32 nodes (g = row[last], v pre-added)
    float bv = NEGINF;
    int bi = NN;  // sentinel
#pragma unroll
    for (int r = 0; r < 8; ++r) {
      float4 d4 = dd4[r * 64 + lane];
      float gl[4] = {g[r].x, g[r].y, g[r].z, g[r].w};
      float dl[4] = {d4.x, d4.y, d4.z, d4.w};
      float cv = NEGINF;
      int cj = 0;
#pragma unroll
      for (int j = 0; j < 4; ++j) {
        // unscaled score: *C0 (exact 2^-6) deferred to the winner — same order
        float tt = fmaf(uu[r * 4 + j], lr, gl[j]);
        bool feas = (dl[j] <= load);  // +inf == visited
        if (feas && tt > cv) { cv = tt; cj = j; }
      }
      // merge in ascending r: strict > keeps the smallest index on ties
      if (cv > bv) { bv = cv; bi = 4 * (r * 64 + lane) + cj; }
    }
    // ---- wave argmax via DPP (result in lane 63), then go scalar
    DPP_MERGE(0x111);  // row_shr:1
    DPP_MERGE(0x112);  // row_shr:2
    DPP_MERGE(0x114);  // row_shr:4
    DPP_MERGE(0x118);  // row_shr:8
    DPP_MERGE(0x142);  // row_bcast:15
    DPP_MERGE(0x143);  // row_bcast:31
    const float rbv = __int_as_float(__builtin_amdgcn_readlane(__float_as_int(bv), 63));
    const int rbi = __builtin_amdgcn_readlane(bi, 63);

    const int take = (rbv > NEGINF);
    const int nxt = take ? rbi : depot;

    // ---- prefetch next row FIRST: bookkeeping below hides under its latency
    if (nxt == depot) {
#pragma unroll
      for (int r = 0; r < 8; ++r) g[r] = dr4[r * 64 + lane];
    } else {
      const float4* rowp = (const float4*)(GT + (size_t)nxt * NN);
#pragma unroll
      for (int r = 0; r < 8; ++r) g[r] = rowp[r * 64 + lane];
    }

    // ---- state update + LDS-buffered outputs
    if (lane == 0) {
      s_tour[1 + step] = (float)nxt;
      s_scr[step] = take ? rbv * C0 : 0.0f;  // exact pow2 scale
    }
    if (take) {
      load = load - s_dem[rbi];  // broadcast LDS read; same fp32 op as reference
      ntaken++;
      if (lane == 0) s_dd[rbi] = INF;  // mark visited
    } else {
      load = capf;
      if (ntaken == NN - 1) done = 1;  // all customers served
    }
    lr = load / capf;  // same fp32 division as reference
  }

  // ---- flush outputs (single wave; LDS writes are in-order visible)
  for (int i = lane; i <= TSTEPS; i += 64) out[i] = s_tour[i];
  for (int i = lane; i < TSTEPS; i += 64) out[1 + TSTEPS + i] = s_scr[i];
}

extern "C" void kernel_launch(void* const* d_in, const int* in_sizes, int n_in,
                              void* d_out, int out_size, void* d_ws, size_t ws_size,
                              hipStream_t stream) {
  const float* emb     = (const float*)d_in[0];  // [N, H]
  const float* demands = (const float*)d_in[1];  // [N]
  const float* Wq      = (const float*)d_in[2];  // [H, H+2]
  const float* bq      = (const float*)d_in[3];  // [H]
  const float* Wk      = (const float*)d_in[4];  // [H, H]
  const float* bk      = (const float*)d_in[5];  // [H]
  const int* cap       = (const int*)d_in[6];
  const int* depot     = (const int*)d_in[7];
  float* out           = (float*)d_out;          // 2305 tour + 2304 scores, fp32

  char* ws = (char*)d_ws;
  float* Kmat = (float*)(ws);                         // 8 MB  [N,H]
  float* Z    = (float*)(ws + ((size_t)8 << 20));     // 8 MB  [N,H]
  float* GT   = (float*)(ws + ((size_t)16 << 20));    // 16 MB [N,N] row=last, +v
  float* Wqh  = (float*)(ws + ((size_t)32 << 20));    // 4 MB  [H,H]
  float* u    = (float*)(ws + ((size_t)36 << 20));    // 8 KB
  float* v    = (float*)(ws + ((size_t)36 << 20) + 8192);

  hipLaunchKernelGGL(prep_wqh, dim3(4096), dim3(256), 0, stream, Wq, Wqh);
  // K = emb @ Wk^T + bk
  hipLaunchKernelGGL(gemm_nt, dim3(HH / TILE, NN / TILE), dim3(256), 0, stream,
                     emb, HH, Wk, HH, Kmat, HH, HH, bk);
  // Z = emb @ Wqh^T
  hipLaunchKernelGGL(gemm_nt, dim3(HH / TILE, NN / TILE), dim3(256), 0, stream,
                     emb, HH, Wqh, HH, Z, HH, HH, (const float*)nullptr);
  // u_i = K_i . Wq[:,H], v_i = K_i . bq   (before GT GEMM: v is its bias)
  hipLaunchKernelGGL(uv_k, dim3(NN), dim3(64), 0, stream, Kmat, Wq, bq, u, v);
  // GT = Z @ K^T + v   (GT[last, i]; v==0 here since bq==0 -> bit-identical)
  hipLaunchKernelGGL(gemm_nt, dim3(NN / TILE, NN / TILE), dim3(256), 0, stream,
                     Z, HH, Kmat, HH, GT, NN, HH, v);
  hipLaunchKernelGGL(decode, dim3(1), dim3(64), 0, stream, GT, u, demands,
                     cap, depot, out);
}